// Round 4
// baseline (535.527 us; speedup 1.0000x reference)
//
#include <hip/hip_runtime.h>
#include <math.h>

// VectorQuantizer on MI355X — round 11: barrier-free k_score (B global->regs).
// latents [64,256,32,32] f32, embedding [1024,256] f32.
// Outputs (concat fp32): quant_st [16777216], loss [1], indices-as-float [65536].
//
// VALIDATED (rounds 2/3/5, absmax 0): numpy index semantics are
//   dist = fl32( fl32(Sx + Ek) - fl32(2*dot) ), argmin first-index ties,
// Sx/Ek = numpy pairwise fp32 (two 128-blocks, 8 accumulators, binary tree),
// dot = sequential ascending-c fp32 FMA chain. MFMA top-2 + margin 3e-4 filter
// + exact re-scan of flagged pixels reproduces it bit-exactly.
//
// HISTORY: r7 LDS-B 2-barrier/chunk + conflicts: 142us. r8/r9 dual-A: spilled.
// r10 LDS-B conflict-free 1-barrier/chunk: 186us, MfmaUtil 15%, VALU 33% --
// BOTH pipes idle -> per-chunk __syncthreads (vmcnt(0) drain) couples waves
// to staging latency; ~2 resident blocks can't fill the bubbles. Any
// B-in-LDS + per-chunk-barrier structure is stuck at 140-190us.
//
// ROUND-11 (k_score; numerics bit-identical to validated round 7):
//  * B fragments loaded global->registers in MFMA layout directly:
//    lane(quad,lane15) reads embHi[(ch*16+lane15)*256 + ks*32 + quad*8 ..+7]
//    (16 rows x 64B coalesced segments; same bytes r7 staged via LDS).
//  * NO LDS for B, NO barriers in the 64-chunk loop. Waves free-run; the
//    matrix pipe is the serializing resource (that's the goal).
//  * Register ping-pong Ba/Bb (8x short8 each), manual 2x unroll, static
//    indexing only. Per-chunk: 8 VMEM + 16 MFMA; prefetch hides under MFMA.
//  * Chain order per chunk: one acc, hi->lo per ks, ascending ks; code visit
//    order ascending n = ch*16+lane15 -> identical top-2/tie semantics.
//  * ~165 VGPR demand; __launch_bounds__(256,2). Spill tripwire: WRITE_SIZE.
//
// Pipeline:
//  k_init    : emb_hi = bf16(emb); blocks 0-3 also Ek[k]; zero loss/count
//  k_score   : MFMA bf16-split engine, per-pixel top-2, margin filter
//  k_refine  : 8 pixels/block-group; 32-code LDS tiles; exact fp32 chains
//  k_gather  : gather + straight-through write + fp64 loss partials
//  k_loss    : loss = 1.25 * total / 16777216

#define DIM 256
#define BSTRIDE 262144
#define OUT_LOSS 16777216
#define OUT_IDX  16777217
#define MARGIN_S 3e-4f

#define RG 8          // refine: pixels per group
#define RTILE 32      // refine: codes per LDS tile
#define RSTRIDE 260   // refine: padded row stride (floats); 260%32=4 -> 4-way max

// ws byte offsets (total 1056768 B)
#define WS_LOSS  0
#define WS_COUNT 8
#define WS_ENORM 64
#define WS_EMBH  8192
#define WS_SEL   532480      // 8192 + 1024*256*2
#define WS_WL    794624      // 532480 + 65536*4

typedef __attribute__((ext_vector_type(8))) short short8;
typedef __attribute__((ext_vector_type(4))) float f32x4;

__device__ inline unsigned short f2bf(float f) {   // RNE f32 -> bf16 bits
  unsigned u = __float_as_uint(f);
  unsigned r = 0x7FFFu + ((u >> 16) & 1u);
  return (unsigned short)((u + r) >> 16);
}
__device__ inline float bf2f(unsigned short h) {
  return __uint_as_float(((unsigned)h) << 16);
}

// ---------------- k_init: embconv + (blocks 0-3) enormQ + zeroing -----------
__global__ void k_init(const float* __restrict__ emb, unsigned short* __restrict__ embHi,
                       float* __restrict__ enormQ, double* __restrict__ lossAcc,
                       int* __restrict__ count) {
  const int t = threadIdx.x;
  if (blockIdx.x == 0 && t == 0) { *lossAcc = 0.0; *count = 0; }
  // embconv part: 256 blocks x 256 threads x 4 floats = 262144
  const int i = (blockIdx.x * 256 + t) * 4;
  float4 v = *(const float4*)(emb + i);
  unsigned r0 = (unsigned)f2bf(v.x) | ((unsigned)f2bf(v.y) << 16);
  unsigned r1 = (unsigned)f2bf(v.z) | ((unsigned)f2bf(v.w) << 16);
  uint2 st; st.x = r0; st.y = r1;
  *(uint2*)(embHi + i) = st;
  // enormQ part: blocks 0-3 cover k = 0..1023 (numpy-pairwise, validated)
  if (blockIdx.x < 4) {
    const int k = blockIdx.x * 256 + t;
    const float* e = emb + (size_t)k * DIM;
    float blk[2];
    #pragma unroll
    for (int h = 0; h < 2; ++h) {
      const float* a = e + h * 128;
      float r[8];
      #pragma unroll
      for (int j = 0; j < 8; ++j) r[j] = __fmul_rn(a[j], a[j]);
      for (int ii = 8; ii < 128; ii += 8)
        #pragma unroll
        for (int j = 0; j < 8; ++j) r[j] = __fadd_rn(r[j], __fmul_rn(a[ii+j], a[ii+j]));
      blk[h] = __fadd_rn(__fadd_rn(__fadd_rn(r[0], r[1]), __fadd_rn(r[2], r[3])),
                         __fadd_rn(__fadd_rn(r[4], r[5]), __fadd_rn(r[6], r[7])));
    }
    enormQ[k] = __fadd_rn(blk[0], blk[1]);
  }
}

// ---------------- k_score: MFMA engine + top-2 filter -----------------------
// 1024 blocks x 256 threads (4 waves). Block = 64 pixels; wave = 16 pixels
// (one 16x16 A tile). 64 chunks x 16 codes; B fragments global->registers
// (ping-pong), no LDS-B, no loop barriers.
// MFMA 16x16x32: A[m=lane&15][k=quad*8+j], B[n=lane&15][k=quad*8+j],
//                D[m=quad*4+reg][n=lane&15].
__launch_bounds__(256, 2)
__global__ void k_score(const float* __restrict__ lat,
                        const unsigned short* __restrict__ embHi,
                        const float* __restrict__ enormQ,
                        int* __restrict__ selIdx, float* __restrict__ out,
                        int* __restrict__ count, int* __restrict__ worklist) {
  __shared__ float sNorm[1024];                       // 4 KB (only LDS)

  const int t = threadIdx.x;
  const int w = t >> 6;          // wave 0..3
  const int L = t & 63;          // lane
  const int lane15 = L & 15;
  const int quad = L >> 4;

  const int pix0 = blockIdx.x * 64;
  const int bImg = pix0 >> 10;
  const int hw0 = pix0 & 1023;

  for (int i = t; i < 1024; i += 256) sNorm[i] = enormQ[i];

  // ---- A fragments: 16 pixels of this wave, all 8 k-steps, hi+lo ----
  // (round-7 proven pattern)
  const int myPixHw = hw0 + w * 16 + lane15;
  const float* latPix = lat + (size_t)bImg * BSTRIDE + myPixHw;
  short8 aHi[8], aLo[8];
  #pragma unroll
  for (int ks = 0; ks < 8; ++ks) {
    #pragma unroll
    for (int j = 0; j < 8; ++j) {
      float f = latPix[(size_t)(ks * 32 + quad * 8 + j) * 1024];
      unsigned short hb = f2bf(f);
      unsigned short lb = f2bf(f - bf2f(hb));
      aHi[ks][j] = (short)hb;
      aLo[ks][j] = (short)lb;
    }
  }

  float b1[4], b2[4];
  int i1[4], i2[4];
  #pragma unroll
  for (int r = 0; r < 4; ++r) { b1[r] = INFINITY; b2[r] = INFINITY; i1[r] = 0x7fffffff; i2[r] = 0x7fffffff; }

  // B fragment base for this lane: row lane15, byte offset quad*16 within row;
  // chunk ch adds ch*16 rows, ks adds ks*64B.
  const unsigned short* bBase = embHi + (size_t)lane15 * 256 + quad * 8;

  // Per-chunk compute: ONE acc, hi->lo per ks ascending, then ascending-n
  // top-2 update — byte-for-byte the validated round-7 chain.
#define SCORE_CHUNK(BREG, CH)                                                  \
  {                                                                            \
    f32x4 acc = {0.f, 0.f, 0.f, 0.f};                                          \
    _Pragma("unroll")                                                          \
    for (int ks = 0; ks < 8; ++ks) {                                           \
      acc = __builtin_amdgcn_mfma_f32_16x16x32_bf16(aHi[ks], BREG[ks], acc, 0, 0, 0); \
      acc = __builtin_amdgcn_mfma_f32_16x16x32_bf16(aLo[ks], BREG[ks], acc, 0, 0, 0); \
    }                                                                          \
    const int n = (CH) * 16 + lane15;                                          \
    const float en = sNorm[n];                                                 \
    _Pragma("unroll")                                                          \
    for (int r = 0; r < 4; ++r) {                                              \
      float s = fmaf(-2.0f, acc[r], en);                                       \
      if (s < b1[r])      { b2[r] = b1[r]; i2[r] = i1[r]; b1[r] = s; i1[r] = n; } \
      else if (s < b2[r]) { b2[r] = s; i2[r] = n; }                            \
    }                                                                          \
  }

  short8 Ba[8], Bb[8];
  #pragma unroll
  for (int ks = 0; ks < 8; ++ks)
    Ba[ks] = *(const short8*)(bBase + (size_t)ks * 32);

  __syncthreads();   // sNorm ready (only barrier in the kernel)

  for (int ch = 0; ch < 64; ch += 2) {
    {  // prefetch chunk ch+1 (always valid: ch max 62 -> 63)
      const unsigned short* p = bBase + (size_t)(ch + 1) * 16 * 256;
      #pragma unroll
      for (int ks = 0; ks < 8; ++ks) Bb[ks] = *(const short8*)(p + (size_t)ks * 32);
    }
    SCORE_CHUNK(Ba, ch)
    if (ch + 2 < 64) {  // prefetch chunk ch+2
      const unsigned short* p = bBase + (size_t)(ch + 2) * 16 * 256;
      #pragma unroll
      for (int ks = 0; ks < 8; ++ks) Ba[ks] = *(const short8*)(p + (size_t)ks * 32);
    }
    SCORE_CHUNK(Bb, ch + 1)
  }
#undef SCORE_CHUNK

  // butterfly top-2 merge across the 16 lanes sharing each pixel
  #pragma unroll
  for (int m = 1; m <= 8; m <<= 1) {
    #pragma unroll
    for (int r = 0; r < 4; ++r) {
      float ob1 = __shfl_xor(b1[r], m), ob2 = __shfl_xor(b2[r], m);
      int oi1 = __shfl_xor(i1[r], m), oi2 = __shfl_xor(i2[r], m);
      bool aF = (b1[r] < ob1) || (b1[r] == ob1 && i1[r] < oi1);
      float w1 = aF ? b1[r] : ob1;  int wi1 = aF ? i1[r] : oi1;
      float lf = aF ? ob1 : b1[r];  int lfi = aF ? oi1 : i1[r];
      float ws = aF ? b2[r] : ob2;  int wsi = aF ? i2[r] : oi2;
      bool sF = (ws < lf) || (ws == lf && wsi < lfi);
      b1[r] = w1; i1[r] = wi1;
      b2[r] = sF ? ws : lf; i2[r] = sF ? wsi : lfi;
    }
  }
  if (lane15 == 0) {
    #pragma unroll
    for (int r = 0; r < 4; ++r) {
      const int pix = pix0 + w * 16 + quad * 4 + r;
      if (b2[r] - b1[r] >= MARGIN_S) {
        selIdx[pix] = i1[r];
        out[OUT_IDX + pix] = (float)i1[r];
      } else {
        int pos = atomicAdd(count, 1);
        worklist[pos] = pix;
      }
    }
  }
}

// ---------------- k_refine v3: LDS mini-GEMM exact re-scan ------------------
// 1024 blocks x 256 threads. Group = RG(8) pixels; wave w covers pixels
// 2w,2w+1 (one per half-wave); lane&31 owns one code of each RTILE(32) tile.
// Codebook tile staged coalesced into LDS (rows padded to 260 floats).
// Dot = validated sequential ascending-c fp32 FMA chain, operands from LDS.
__launch_bounds__(256, 2)
__global__ void k_refine(const float* __restrict__ lat, const float* __restrict__ emb,
                         const float* __restrict__ enormQ,
                         const int* __restrict__ count, const int* __restrict__ worklist,
                         int* __restrict__ selIdx, float* __restrict__ out) {
  __shared__ __align__(16) float sE[RTILE * RSTRIDE];   // 33,280 B
  __shared__ __align__(16) float sX[RG * RSTRIDE];      // 8,320 B
  __shared__ float sSx[RG];
  const int t = threadIdx.x;
  const int cnt = *count;
  if (cnt == 0) return;
  const int ngroups = (cnt + RG - 1) / RG;
  const int w = t >> 6, lane = t & 63;
  const int sub = lane >> 5;           // half-wave: 0 or 1
  const int kLane = lane & 31;         // code slot within tile
  const int pixSlot = w * 2 + sub;     // 0..7

  for (int g = blockIdx.x; g < ngroups; g += gridDim.x) {
    // ---- stage RG pixels' latents (tail pixels clamped, never written) ----
    {
      const int p = t >> 5, c0 = t & 31;    // 32 threads per pixel
      int wi = g * RG + p; if (wi >= cnt) wi = cnt - 1;
      const int pix = worklist[wi];
      const float* latB = lat + (size_t)(pix >> 10) * BSTRIDE + (pix & 1023);
      #pragma unroll
      for (int i = 0; i < 8; ++i) {
        int c = c0 + 32 * i;
        sX[p * RSTRIDE + c] = latB[(size_t)c * 1024];
      }
    }
    __syncthreads();
    // ---- per-pixel numpy-pairwise Sx (threads 0..RG-1) ----
    if (t < RG) {
      const float* a0 = sX + t * RSTRIDE;
      float blk[2];
      #pragma unroll
      for (int h = 0; h < 2; ++h) {
        const float* a = a0 + h * 128;
        float r[8];
        #pragma unroll
        for (int j = 0; j < 8; ++j) r[j] = __fmul_rn(a[j], a[j]);
        for (int i = 8; i < 128; i += 8)
          #pragma unroll
          for (int j = 0; j < 8; ++j) r[j] = __fadd_rn(r[j], __fmul_rn(a[i+j], a[i+j]));
        blk[h] = __fadd_rn(__fadd_rn(__fadd_rn(r[0], r[1]), __fadd_rn(r[2], r[3])),
                           __fadd_rn(__fadd_rn(r[4], r[5]), __fadd_rn(r[6], r[7])));
      }
      sSx[t] = __fadd_rn(blk[0], blk[1]);
    }

    float best = INFINITY; int bi = 0x7fffffff;
    const float* xrow = sX + pixSlot * RSTRIDE;
    for (int tile = 0; tile < 32; ++tile) {
      __syncthreads();   // prev-tile reads done (also orders sSx writes)
      // stage tile: 32 rows x 256 floats (64 float4/row; 8 threads/row x 8)
      {
        const int r = t >> 3, q0 = t & 7;   // 8 threads per row
        const float* src = emb + (size_t)(tile * RTILE + r) * 256;
        #pragma unroll
        for (int i = 0; i < 8; ++i) {
          int q = q0 + 8 * i;
          *(float4*)(sE + r * RSTRIDE + q * 4) = *(const float4*)(src + q * 4);
        }
      }
      __syncthreads();
      // exact ascending-c chain from LDS
      const float* erow = sE + kLane * RSTRIDE;
      float d = 0.f;
      for (int c = 0; c < 256; c += 4) {
        float4 xv = *(const float4*)(xrow + c);
        float4 ev = *(const float4*)(erow + c);
        d = fmaf(xv.x, ev.x, d); d = fmaf(xv.y, ev.y, d);
        d = fmaf(xv.z, ev.z, d); d = fmaf(xv.w, ev.w, d);
      }
      const int k = tile * RTILE + kLane;
      float dq = __fsub_rn(__fadd_rn(sSx[pixSlot], enormQ[k]), __fmul_rn(2.0f, d));
      if (dq < best) { best = dq; bi = k; }   // ascending k per lane
    }
    // lexicographic reduce within each half-wave (pre-update read semantics
    // keep the tree correct; polluted upper lanes are never re-consumed)
    for (int off = 16; off > 0; off >>= 1) {
      float ob = __shfl_down(best, off);
      int oi = __shfl_down(bi, off);
      if (ob < best || (ob == best && oi < bi)) { best = ob; bi = oi; }
    }
    if (kLane == 0) {
      const int wi = g * RG + pixSlot;
      if (wi < cnt) {
        const int pix = worklist[wi];
        selIdx[pix] = bi;
        out[OUT_IDX + pix] = (float)bi;
      }
    }
    __syncthreads();   // sX/sSx stable until all waves finish the group
  }
}

// ---------------- k_gather: gather + straight-through + loss ----------------
__global__ void k_gather(const float* __restrict__ lat, const float* __restrict__ emb,
                         const int* __restrict__ selIdx,
                         float* __restrict__ out, double* __restrict__ lossAcc) {
  __shared__ int sIdx[64];
  const int t = threadIdx.x;
  const int pix0 = blockIdx.x * 64;
  const int b = pix0 >> 10;
  const int hw0 = pix0 & 1023;
  const float* latBase = lat + (size_t)b * BSTRIDE + hw0;

  if (t < 64) sIdx[t] = selIdx[pix0 + t];
  __syncthreads();

  const int cSub = t >> 4;
  const int p4 = (t & 15) * 4;
  const int k0 = sIdx[p4], k1 = sIdx[p4+1], k2 = sIdx[p4+2], k3 = sIdx[p4+3];
  double lsum = 0.0;
  #pragma unroll 4
  for (int i = 0; i < 16; ++i) {
    int c = i * 16 + cSub;
    float4 l = *(const float4*)(latBase + (size_t)c * 1024 + p4);
    float q0 = emb[k0 * DIM + c], q1 = emb[k1 * DIM + c],
          q2 = emb[k2 * DIM + c], q3 = emb[k3 * DIM + c];
    float d0 = q0 - l.x, d1 = q1 - l.y, d2 = q2 - l.z, d3 = q3 - l.w;
    float4 o; o.x = l.x + d0; o.y = l.y + d1; o.z = l.z + d2; o.w = l.w + d3;
    *(float4*)(out + (size_t)b * BSTRIDE + (size_t)c * 1024 + hw0 + p4) = o;
    lsum += (double)d0*d0 + (double)d1*d1 + (double)d2*d2 + (double)d3*d3;
  }
  for (int off = 32; off > 0; off >>= 1) lsum += __shfl_down(lsum, off);
  if ((t & 63) == 0) atomicAdd(lossAcc, lsum);
}

__global__ void k_loss(const double* __restrict__ lossAcc, float* __restrict__ out) {
  double m = *lossAcc * (1.0 / 16777216.0);
  out[OUT_LOSS] = (float)(1.25 * m);
}

extern "C" void kernel_launch(void* const* d_in, const int* in_sizes, int n_in,
                              void* d_out, int out_size, void* d_ws, size_t ws_size,
                              hipStream_t stream) {
  const float* lat = (const float*)d_in[0];
  const float* emb = (const float*)d_in[1];
  float* out = (float*)d_out;
  char* ws = (char*)d_ws;
  double* lossAcc = (double*)(ws + WS_LOSS);
  int* count = (int*)(ws + WS_COUNT);
  float* enormQ = (float*)(ws + WS_ENORM);
  unsigned short* embHi = (unsigned short*)(ws + WS_EMBH);
  int* selIdx = (int*)(ws + WS_SEL);
  int* worklist = (int*)(ws + WS_WL);

  k_init<<<dim3(256), dim3(256), 0, stream>>>(emb, embHi, enormQ, lossAcc, count);
  k_score<<<dim3(1024), dim3(256), 0, stream>>>(lat, embHi, enormQ, selIdx, out, count, worklist);
  k_refine<<<dim3(1024), dim3(256), 0, stream>>>(lat, emb, enormQ, count, worklist, selIdx, out);
  k_gather<<<dim3(1024), dim3(256), 0, stream>>>(lat, emb, selIdx, out, lossAcc);
  k_loss<<<dim3(1), dim3(1), 0, stream>>>(lossAcc, out);
}

// Round 5
// 396.080 us; speedup vs baseline: 1.3521x; 1.3521x over previous
//
#include <hip/hip_runtime.h>
#include <math.h>

// VectorQuantizer on MI355X — round 12: r7 structure + conflict-free B layout.
// latents [64,256,32,32] f32, embedding [1024,256] f32.
// Outputs (concat fp32): quant_st [16777216], loss [1], indices-as-float [65536].
//
// VALIDATED (rounds 2/3/5, absmax 0): numpy index semantics are
//   dist = fl32( fl32(Sx + Ek) - fl32(2*dot) ), argmin first-index ties,
// Sx/Ek = numpy pairwise fp32 (two 128-blocks, 8 accumulators, binary tree),
// dot = sequential ascending-c fp32 FMA chain. MFMA top-2 + margin 3e-4 filter
// + exact re-scan of flagged pixels reproduces it bit-exactly.
//
// STRUCTURE RANKING (measured): r7 reg-staged LDS-B 2-barrier w/ 8.4M conflict
// cycles = 142us BEST; r10 gload_lds 1-barrier 0-conflict = 186us (barrier
// couples waves to staging latency); r11 reg-B 0-barrier = 285us (per-wave L2
// latency exposed). r8/r9 dual-A = spills. Conclusion: keep r7's pipeline,
// fix ONLY the layout.
//
// ROUND-12 (k_score; bit-identical numerics to r7):
//  * LDS slot s = o*16 + n (o = dim-octet 0..31, n = code 0..15). Frag read
//    (ks,quad): slot (ks*4+quad)*16+lane15 -> wave reads contiguous 1KB ->
//    0 bank conflicts (r8/r10-proven pattern; r7's 264-short rows cost 8.4M
//    conflict cycles).
//  * Staging: thread t loads row ch*16+(t&15), octets t>>4 / 16+(t>>4)
//    (16x64B L2 segments), writes slots t / 256+t -> wave-contiguous 1KB
//    writes, conflict-free. LDS 20.9 -> 16KB (+4KB sNorm).
//  * Everything else = r7 byte-for-byte: reg-staged double-buffer, 2 barriers
//    per chunk, 64 chunks x 16 codes, one acc, hi->lo per ks ascending,
//    code order n = ch*16+lane15 -> identical top-2/tie -> refine unchanged.
//
// Pipeline:
//  k_init    : emb_hi = bf16(emb); blocks 0-3 also Ek[k]; zero loss/count
//  k_score   : MFMA bf16-split engine, per-pixel top-2, margin filter
//  k_refine  : 8 pixels/block-group; 32-code LDS tiles; exact fp32 chains
//  k_gather  : gather + straight-through write + fp64 loss partials
//  k_loss    : loss = 1.25 * total / 16777216

#define DIM 256
#define BSTRIDE 262144
#define OUT_LOSS 16777216
#define OUT_IDX  16777217
#define MARGIN_S 3e-4f

#define RG 8          // refine: pixels per group
#define RTILE 32      // refine: codes per LDS tile
#define RSTRIDE 260   // refine: padded row stride (floats); 260%32=4 -> 4-way max

// ws byte offsets (total 1056768 B)
#define WS_LOSS  0
#define WS_COUNT 8
#define WS_ENORM 64
#define WS_EMBH  8192
#define WS_SEL   532480      // 8192 + 1024*256*2
#define WS_WL    794624      // 532480 + 65536*4

typedef __attribute__((ext_vector_type(8))) short short8;
typedef __attribute__((ext_vector_type(4))) float f32x4;

__device__ inline unsigned short f2bf(float f) {   // RNE f32 -> bf16 bits
  unsigned u = __float_as_uint(f);
  unsigned r = 0x7FFFu + ((u >> 16) & 1u);
  return (unsigned short)((u + r) >> 16);
}
__device__ inline float bf2f(unsigned short h) {
  return __uint_as_float(((unsigned)h) << 16);
}

// ---------------- k_init: embconv + (blocks 0-3) enormQ + zeroing -----------
__global__ void k_init(const float* __restrict__ emb, unsigned short* __restrict__ embHi,
                       float* __restrict__ enormQ, double* __restrict__ lossAcc,
                       int* __restrict__ count) {
  const int t = threadIdx.x;
  if (blockIdx.x == 0 && t == 0) { *lossAcc = 0.0; *count = 0; }
  // embconv part: 256 blocks x 256 threads x 4 floats = 262144
  const int i = (blockIdx.x * 256 + t) * 4;
  float4 v = *(const float4*)(emb + i);
  unsigned r0 = (unsigned)f2bf(v.x) | ((unsigned)f2bf(v.y) << 16);
  unsigned r1 = (unsigned)f2bf(v.z) | ((unsigned)f2bf(v.w) << 16);
  uint2 st; st.x = r0; st.y = r1;
  *(uint2*)(embHi + i) = st;
  // enormQ part: blocks 0-3 cover k = 0..1023 (numpy-pairwise, validated)
  if (blockIdx.x < 4) {
    const int k = blockIdx.x * 256 + t;
    const float* e = emb + (size_t)k * DIM;
    float blk[2];
    #pragma unroll
    for (int h = 0; h < 2; ++h) {
      const float* a = e + h * 128;
      float r[8];
      #pragma unroll
      for (int j = 0; j < 8; ++j) r[j] = __fmul_rn(a[j], a[j]);
      for (int ii = 8; ii < 128; ii += 8)
        #pragma unroll
        for (int j = 0; j < 8; ++j) r[j] = __fadd_rn(r[j], __fmul_rn(a[ii+j], a[ii+j]));
      blk[h] = __fadd_rn(__fadd_rn(__fadd_rn(r[0], r[1]), __fadd_rn(r[2], r[3])),
                         __fadd_rn(__fadd_rn(r[4], r[5]), __fadd_rn(r[6], r[7])));
    }
    enormQ[k] = __fadd_rn(blk[0], blk[1]);
  }
}

// ---------------- k_score: MFMA engine + top-2 filter -----------------------
// 1024 blocks x 256 threads (4 waves). Block = 64 pixels; wave = 16 pixels.
// A (16 pix x 256 feats, hi+lo bf16) register-resident. B (16 codes/chunk)
// reg-staged double-buffered LDS, octet-major slots (s = o*16 + n).
// MFMA 16x16x32: A[m=lane&15][k=quad*8+j], B[n=lane&15][k=quad*8+j],
//                D[m=quad*4+reg][n=lane&15].
__launch_bounds__(256, 2)
__global__ void k_score(const float* __restrict__ lat,
                        const unsigned short* __restrict__ embHi,
                        const float* __restrict__ enormQ,
                        int* __restrict__ selIdx, float* __restrict__ out,
                        int* __restrict__ count, int* __restrict__ worklist) {
  __shared__ __align__(16) unsigned short sB[2 * 4096];  // 2 x 512 slots x 8 = 16KB
  __shared__ float sNorm[1024];                          // 4 KB

  const int t = threadIdx.x;
  const int w = t >> 6;          // wave 0..3
  const int L = t & 63;          // lane
  const int lane15 = L & 15;
  const int quad = L >> 4;

  const int pix0 = blockIdx.x * 64;
  const int bImg = pix0 >> 10;
  const int hw0 = pix0 & 1023;

  for (int i = t; i < 1024; i += 256) sNorm[i] = enormQ[i];

  // ---- A fragments: 16 pixels of this wave, all 8 k-steps, hi+lo ----
  // (r7 proven pattern: no spill)
  const int myPixHw = hw0 + w * 16 + lane15;
  const float* latPix = lat + (size_t)bImg * BSTRIDE + myPixHw;
  short8 aHi[8], aLo[8];
  #pragma unroll
  for (int ks = 0; ks < 8; ++ks) {
    #pragma unroll
    for (int j = 0; j < 8; ++j) {
      float f = latPix[(size_t)(ks * 32 + quad * 8 + j) * 1024];
      unsigned short hb = f2bf(f);
      unsigned short lb = f2bf(f - bf2f(hb));
      aHi[ks][j] = (short)hb;
      aLo[ks][j] = (short)lb;
    }
  }

  float b1[4], b2[4];
  int i1[4], i2[4];
  #pragma unroll
  for (int r = 0; r < 4; ++r) { b1[r] = INFINITY; b2[r] = INFINITY; i1[r] = 0x7fffffff; i2[r] = 0x7fffffff; }

  // staging map (octet-major dest, conflict-free both sides):
  //   thread t: code n = t&15 of the chunk; octets o0 = t>>4, o1 = 16+(t>>4)
  //   src: embHi[(ch*16+n)*256 + o*8], 16B each (16 rows x 64B segments/wave)
  //   dst slots: s0 = o0*16+n = t, s1 = o1*16+n = 256+t (wave-contiguous 1KB)
  const int nCode = t & 15;
  const int oct0 = t >> 4;
  const unsigned short* srcRowBase = embHi + (size_t)nCode * 256 + oct0 * 8;

  {
    short8 p0 = *(const short8*)(srcRowBase);          // chunk 0, octet o0
    short8 p1 = *(const short8*)(srcRowBase + 128);    // chunk 0, octet o1 (+256B)
    *(short8*)(sB + (size_t)t * 8) = p0;
    *(short8*)(sB + (size_t)(256 + t) * 8) = p1;
  }
  __syncthreads();

  for (int ch = 0; ch < 64; ++ch) {
    const int cur = ch & 1;
    short8 p0, p1;
    if (ch < 63) {   // load chunk ch+1 into regs; latency hidden by compute
      const unsigned short* src = srcRowBase + (size_t)(ch + 1) * 16 * 256;
      p0 = *(const short8*)(src);
      p1 = *(const short8*)(src + 128);
    }
    f32x4 acc = {0.f, 0.f, 0.f, 0.f};
    const unsigned short* bbuf = sB + cur * 4096;
    #pragma unroll
    for (int ks = 0; ks < 8; ++ks) {
      // slot (ks*4+quad)*16 + lane15: wave reads contiguous 1KB, 0 conflicts
      short8 bfrag = *(const short8*)(bbuf + (size_t)(((ks * 4 + quad) * 16) + lane15) * 8);
      acc = __builtin_amdgcn_mfma_f32_16x16x32_bf16(aHi[ks], bfrag, acc, 0, 0, 0);
      acc = __builtin_amdgcn_mfma_f32_16x16x32_bf16(aLo[ks], bfrag, acc, 0, 0, 0);
    }
    const int n = ch * 16 + lane15;
    const float en = sNorm[n];
    #pragma unroll
    for (int r = 0; r < 4; ++r) {
      float s = fmaf(-2.0f, acc[r], en);
      if (s < b1[r])      { b2[r] = b1[r]; i2[r] = i1[r]; b1[r] = s; i1[r] = n; }
      else if (s < b2[r]) { b2[r] = s; i2[r] = n; }
    }
    if (ch < 63) {
      __syncthreads();   // all waves done reading buf[1-cur] (prev chunk)
      unsigned short* nb = sB + (1 - cur) * 4096;
      *(short8*)(nb + (size_t)t * 8) = p0;
      *(short8*)(nb + (size_t)(256 + t) * 8) = p1;
      __syncthreads();   // writes visible before next chunk's reads
    }
  }

  // butterfly top-2 merge across the 16 lanes sharing each pixel
  #pragma unroll
  for (int m = 1; m <= 8; m <<= 1) {
    #pragma unroll
    for (int r = 0; r < 4; ++r) {
      float ob1 = __shfl_xor(b1[r], m), ob2 = __shfl_xor(b2[r], m);
      int oi1 = __shfl_xor(i1[r], m), oi2 = __shfl_xor(i2[r], m);
      bool aF = (b1[r] < ob1) || (b1[r] == ob1 && i1[r] < oi1);
      float w1 = aF ? b1[r] : ob1;  int wi1 = aF ? i1[r] : oi1;
      float lf = aF ? ob1 : b1[r];  int lfi = aF ? oi1 : i1[r];
      float ws = aF ? b2[r] : ob2;  int wsi = aF ? i2[r] : oi2;
      bool sF = (ws < lf) || (ws == lf && wsi < lfi);
      b1[r] = w1; i1[r] = wi1;
      b2[r] = sF ? ws : lf; i2[r] = sF ? wsi : lfi;
    }
  }
  if (lane15 == 0) {
    #pragma unroll
    for (int r = 0; r < 4; ++r) {
      const int pix = pix0 + w * 16 + quad * 4 + r;
      if (b2[r] - b1[r] >= MARGIN_S) {
        selIdx[pix] = i1[r];
        out[OUT_IDX + pix] = (float)i1[r];
      } else {
        int pos = atomicAdd(count, 1);
        worklist[pos] = pix;
      }
    }
  }
}

// ---------------- k_refine v3: LDS mini-GEMM exact re-scan ------------------
// 1024 blocks x 256 threads. Group = RG(8) pixels; wave w covers pixels
// 2w,2w+1 (one per half-wave); lane&31 owns one code of each RTILE(32) tile.
// Codebook tile staged coalesced into LDS (rows padded to 260 floats).
// Dot = validated sequential ascending-c fp32 FMA chain, operands from LDS.
__launch_bounds__(256, 2)
__global__ void k_refine(const float* __restrict__ lat, const float* __restrict__ emb,
                         const float* __restrict__ enormQ,
                         const int* __restrict__ count, const int* __restrict__ worklist,
                         int* __restrict__ selIdx, float* __restrict__ out) {
  __shared__ __align__(16) float sE[RTILE * RSTRIDE];   // 33,280 B
  __shared__ __align__(16) float sX[RG * RSTRIDE];      // 8,320 B
  __shared__ float sSx[RG];
  const int t = threadIdx.x;
  const int cnt = *count;
  if (cnt == 0) return;
  const int ngroups = (cnt + RG - 1) / RG;
  const int w = t >> 6, lane = t & 63;
  const int sub = lane >> 5;           // half-wave: 0 or 1
  const int kLane = lane & 31;         // code slot within tile
  const int pixSlot = w * 2 + sub;     // 0..7

  for (int g = blockIdx.x; g < ngroups; g += gridDim.x) {
    // ---- stage RG pixels' latents (tail pixels clamped, never written) ----
    {
      const int p = t >> 5, c0 = t & 31;    // 32 threads per pixel
      int wi = g * RG + p; if (wi >= cnt) wi = cnt - 1;
      const int pix = worklist[wi];
      const float* latB = lat + (size_t)(pix >> 10) * BSTRIDE + (pix & 1023);
      #pragma unroll
      for (int i = 0; i < 8; ++i) {
        int c = c0 + 32 * i;
        sX[p * RSTRIDE + c] = latB[(size_t)c * 1024];
      }
    }
    __syncthreads();
    // ---- per-pixel numpy-pairwise Sx (threads 0..RG-1) ----
    if (t < RG) {
      const float* a0 = sX + t * RSTRIDE;
      float blk[2];
      #pragma unroll
      for (int h = 0; h < 2; ++h) {
        const float* a = a0 + h * 128;
        float r[8];
        #pragma unroll
        for (int j = 0; j < 8; ++j) r[j] = __fmul_rn(a[j], a[j]);
        for (int i = 8; i < 128; i += 8)
          #pragma unroll
          for (int j = 0; j < 8; ++j) r[j] = __fadd_rn(r[j], __fmul_rn(a[i+j], a[i+j]));
        blk[h] = __fadd_rn(__fadd_rn(__fadd_rn(r[0], r[1]), __fadd_rn(r[2], r[3])),
                           __fadd_rn(__fadd_rn(r[4], r[5]), __fadd_rn(r[6], r[7])));
      }
      sSx[t] = __fadd_rn(blk[0], blk[1]);
    }

    float best = INFINITY; int bi = 0x7fffffff;
    const float* xrow = sX + pixSlot * RSTRIDE;
    for (int tile = 0; tile < 32; ++tile) {
      __syncthreads();   // prev-tile reads done (also orders sSx writes)
      // stage tile: 32 rows x 256 floats (64 float4/row; 8 threads/row x 8)
      {
        const int r = t >> 3, q0 = t & 7;   // 8 threads per row
        const float* src = emb + (size_t)(tile * RTILE + r) * 256;
        #pragma unroll
        for (int i = 0; i < 8; ++i) {
          int q = q0 + 8 * i;
          *(float4*)(sE + r * RSTRIDE + q * 4) = *(const float4*)(src + q * 4);
        }
      }
      __syncthreads();
      // exact ascending-c chain from LDS
      const float* erow = sE + kLane * RSTRIDE;
      float d = 0.f;
      for (int c = 0; c < 256; c += 4) {
        float4 xv = *(const float4*)(xrow + c);
        float4 ev = *(const float4*)(erow + c);
        d = fmaf(xv.x, ev.x, d); d = fmaf(xv.y, ev.y, d);
        d = fmaf(xv.z, ev.z, d); d = fmaf(xv.w, ev.w, d);
      }
      const int k = tile * RTILE + kLane;
      float dq = __fsub_rn(__fadd_rn(sSx[pixSlot], enormQ[k]), __fmul_rn(2.0f, d));
      if (dq < best) { best = dq; bi = k; }   // ascending k per lane
    }
    // lexicographic reduce within each half-wave (pre-update read semantics
    // keep the tree correct; polluted upper lanes are never re-consumed)
    for (int off = 16; off > 0; off >>= 1) {
      float ob = __shfl_down(best, off);
      int oi = __shfl_down(bi, off);
      if (ob < best || (ob == best && oi < bi)) { best = ob; bi = oi; }
    }
    if (kLane == 0) {
      const int wi = g * RG + pixSlot;
      if (wi < cnt) {
        const int pix = worklist[wi];
        selIdx[pix] = bi;
        out[OUT_IDX + pix] = (float)bi;
      }
    }
    __syncthreads();   // sX/sSx stable until all waves finish the group
  }
}

// ---------------- k_gather: gather + straight-through + loss ----------------
__global__ void k_gather(const float* __restrict__ lat, const float* __restrict__ emb,
                         const int* __restrict__ selIdx,
                         float* __restrict__ out, double* __restrict__ lossAcc) {
  __shared__ int sIdx[64];
  const int t = threadIdx.x;
  const int pix0 = blockIdx.x * 64;
  const int b = pix0 >> 10;
  const int hw0 = pix0 & 1023;
  const float* latBase = lat + (size_t)b * BSTRIDE + hw0;

  if (t < 64) sIdx[t] = selIdx[pix0 + t];
  __syncthreads();

  const int cSub = t >> 4;
  const int p4 = (t & 15) * 4;
  const int k0 = sIdx[p4], k1 = sIdx[p4+1], k2 = sIdx[p4+2], k3 = sIdx[p4+3];
  double lsum = 0.0;
  #pragma unroll 4
  for (int i = 0; i < 16; ++i) {
    int c = i * 16 + cSub;
    float4 l = *(const float4*)(latBase + (size_t)c * 1024 + p4);
    float q0 = emb[k0 * DIM + c], q1 = emb[k1 * DIM + c],
          q2 = emb[k2 * DIM + c], q3 = emb[k3 * DIM + c];
    float d0 = q0 - l.x, d1 = q1 - l.y, d2 = q2 - l.z, d3 = q3 - l.w;
    float4 o; o.x = l.x + d0; o.y = l.y + d1; o.z = l.z + d2; o.w = l.w + d3;
    *(float4*)(out + (size_t)b * BSTRIDE + (size_t)c * 1024 + hw0 + p4) = o;
    lsum += (double)d0*d0 + (double)d1*d1 + (double)d2*d2 + (double)d3*d3;
  }
  for (int off = 32; off > 0; off >>= 1) lsum += __shfl_down(lsum, off);
  if ((t & 63) == 0) atomicAdd(lossAcc, lsum);
}

__global__ void k_loss(const double* __restrict__ lossAcc, float* __restrict__ out) {
  double m = *lossAcc * (1.0 / 16777216.0);
  out[OUT_LOSS] = (float)(1.25 * m);
}

extern "C" void kernel_launch(void* const* d_in, const int* in_sizes, int n_in,
                              void* d_out, int out_size, void* d_ws, size_t ws_size,
                              hipStream_t stream) {
  const float* lat = (const float*)d_in[0];
  const float* emb = (const float*)d_in[1];
  float* out = (float*)d_out;
  char* ws = (char*)d_ws;
  double* lossAcc = (double*)(ws + WS_LOSS);
  int* count = (int*)(ws + WS_COUNT);
  float* enormQ = (float*)(ws + WS_ENORM);
  unsigned short* embHi = (unsigned short*)(ws + WS_EMBH);
  int* selIdx = (int*)(ws + WS_SEL);
  int* worklist = (int*)(ws + WS_WL);

  k_init<<<dim3(256), dim3(256), 0, stream>>>(emb, embHi, enormQ, lossAcc, count);
  k_score<<<dim3(1024), dim3(256), 0, stream>>>(lat, embHi, enormQ, selIdx, out, count, worklist);
  k_refine<<<dim3(1024), dim3(256), 0, stream>>>(lat, emb, enormQ, count, worklist, selIdx, out);
  k_gather<<<dim3(1024), dim3(256), 0, stream>>>(lat, emb, selIdx, out, lossAcc);
  k_loss<<<dim3(1), dim3(1), 0, stream>>>(lossAcc, out);
}

// Round 6
// 378.895 us; speedup vs baseline: 1.4134x; 1.0454x over previous
//
#include <hip/hip_runtime.h>
#include <math.h>

// VectorQuantizer on MI355X — round 13: raise k_score occupancy 2->4 blocks/CU.
// latents [64,256,32,32] f32, embedding [1024,256] f32.
// Outputs (concat fp32): quant_st [16777216], loss [1], indices-as-float [65536].
//
// VALIDATED (rounds 2/3/5, absmax 0): numpy index semantics are
//   dist = fl32( fl32(Sx + Ek) - fl32(2*dot) ), argmin first-index ties,
// Sx/Ek = numpy pairwise fp32 (two 128-blocks, 8 accumulators, binary tree),
// dot = sequential ascending-c fp32 FMA chain. MFMA top-2 + margin 3e-4 filter
// + exact re-scan of flagged pixels reproduces it bit-exactly.
//
// STRUCTURE RANKING (measured): r7/r12 reg-staged LDS-B 2-barrier = 140-142us
// BEST; r10 gload_lds 1-barrier = 186us; r11 reg-B 0-barrier = 285us;
// r8/r9 dual-A = spills. r12 zeroed bank conflicts (8.4M->0) with NO dur
// change -> conflicts were masked by the dominant stall.
//
// ROUND-13 (one variable): counters show MfmaUtil 20%, VALU 45%, HBM 3%,
// conflicts 0 -- no pipe saturated; OccupancyPercent 25% = 2 blocks/CU pinned
// by __launch_bounds__(256,2). The 2-phase barrier loop (128 crossings) has
// nothing to overlap its sync stalls. Fix: __launch_bounds__(256,4) -> 4
// resident blocks/CU (VGPR 84<=128 cap OK, LDS 4x20.5KB=82KB<=160KB OK,
// grid 1024 = 256CU x 4 fully resident). Numerics untouched.
//
// Pipeline:
//  k_init    : emb_hi = bf16(emb); blocks 0-3 also Ek[k]; zero loss/count
//  k_score   : MFMA bf16-split engine, per-pixel top-2, margin filter
//  k_refine  : 8 pixels/block-group; 32-code LDS tiles; exact fp32 chains
//  k_gather  : gather + straight-through write + fp64 loss partials
//  k_loss    : loss = 1.25 * total / 16777216

#define DIM 256
#define BSTRIDE 262144
#define OUT_LOSS 16777216
#define OUT_IDX  16777217
#define MARGIN_S 3e-4f

#define RG 8          // refine: pixels per group
#define RTILE 32      // refine: codes per LDS tile
#define RSTRIDE 260   // refine: padded row stride (floats); 260%32=4 -> 4-way max

// ws byte offsets (total 1056768 B)
#define WS_LOSS  0
#define WS_COUNT 8
#define WS_ENORM 64
#define WS_EMBH  8192
#define WS_SEL   532480      // 8192 + 1024*256*2
#define WS_WL    794624      // 532480 + 65536*4

typedef __attribute__((ext_vector_type(8))) short short8;
typedef __attribute__((ext_vector_type(4))) float f32x4;

__device__ inline unsigned short f2bf(float f) {   // RNE f32 -> bf16 bits
  unsigned u = __float_as_uint(f);
  unsigned r = 0x7FFFu + ((u >> 16) & 1u);
  return (unsigned short)((u + r) >> 16);
}
__device__ inline float bf2f(unsigned short h) {
  return __uint_as_float(((unsigned)h) << 16);
}

// ---------------- k_init: embconv + (blocks 0-3) enormQ + zeroing -----------
__global__ void k_init(const float* __restrict__ emb, unsigned short* __restrict__ embHi,
                       float* __restrict__ enormQ, double* __restrict__ lossAcc,
                       int* __restrict__ count) {
  const int t = threadIdx.x;
  if (blockIdx.x == 0 && t == 0) { *lossAcc = 0.0; *count = 0; }
  // embconv part: 256 blocks x 256 threads x 4 floats = 262144
  const int i = (blockIdx.x * 256 + t) * 4;
  float4 v = *(const float4*)(emb + i);
  unsigned r0 = (unsigned)f2bf(v.x) | ((unsigned)f2bf(v.y) << 16);
  unsigned r1 = (unsigned)f2bf(v.z) | ((unsigned)f2bf(v.w) << 16);
  uint2 st; st.x = r0; st.y = r1;
  *(uint2*)(embHi + i) = st;
  // enormQ part: blocks 0-3 cover k = 0..1023 (numpy-pairwise, validated)
  if (blockIdx.x < 4) {
    const int k = blockIdx.x * 256 + t;
    const float* e = emb + (size_t)k * DIM;
    float blk[2];
    #pragma unroll
    for (int h = 0; h < 2; ++h) {
      const float* a = e + h * 128;
      float r[8];
      #pragma unroll
      for (int j = 0; j < 8; ++j) r[j] = __fmul_rn(a[j], a[j]);
      for (int ii = 8; ii < 128; ii += 8)
        #pragma unroll
        for (int j = 0; j < 8; ++j) r[j] = __fadd_rn(r[j], __fmul_rn(a[ii+j], a[ii+j]));
      blk[h] = __fadd_rn(__fadd_rn(__fadd_rn(r[0], r[1]), __fadd_rn(r[2], r[3])),
                         __fadd_rn(__fadd_rn(r[4], r[5]), __fadd_rn(r[6], r[7])));
    }
    enormQ[k] = __fadd_rn(blk[0], blk[1]);
  }
}

// ---------------- k_score: MFMA engine + top-2 filter -----------------------
// 1024 blocks x 256 threads (4 waves). Block = 64 pixels; wave = 16 pixels.
// A (16 pix x 256 feats, hi+lo bf16) register-resident. B (16 codes/chunk)
// reg-staged double-buffered LDS, octet-major slots (s = o*16 + n).
// MFMA 16x16x32: A[m=lane&15][k=quad*8+j], B[n=lane&15][k=quad*8+j],
//                D[m=quad*4+reg][n=lane&15].
// __launch_bounds__(256,4): 4 blocks/CU resident (VGPR cap 128; demand 84).
__launch_bounds__(256, 4)
__global__ void k_score(const float* __restrict__ lat,
                        const unsigned short* __restrict__ embHi,
                        const float* __restrict__ enormQ,
                        int* __restrict__ selIdx, float* __restrict__ out,
                        int* __restrict__ count, int* __restrict__ worklist) {
  __shared__ __align__(16) unsigned short sB[2 * 4096];  // 2 x 512 slots x 8 = 16KB
  __shared__ float sNorm[1024];                          // 4 KB

  const int t = threadIdx.x;
  const int w = t >> 6;          // wave 0..3
  const int L = t & 63;          // lane
  const int lane15 = L & 15;
  const int quad = L >> 4;

  const int pix0 = blockIdx.x * 64;
  const int bImg = pix0 >> 10;
  const int hw0 = pix0 & 1023;

  for (int i = t; i < 1024; i += 256) sNorm[i] = enormQ[i];

  // ---- A fragments: 16 pixels of this wave, all 8 k-steps, hi+lo ----
  // (r7 proven pattern: no spill)
  const int myPixHw = hw0 + w * 16 + lane15;
  const float* latPix = lat + (size_t)bImg * BSTRIDE + myPixHw;
  short8 aHi[8], aLo[8];
  #pragma unroll
  for (int ks = 0; ks < 8; ++ks) {
    #pragma unroll
    for (int j = 0; j < 8; ++j) {
      float f = latPix[(size_t)(ks * 32 + quad * 8 + j) * 1024];
      unsigned short hb = f2bf(f);
      unsigned short lb = f2bf(f - bf2f(hb));
      aHi[ks][j] = (short)hb;
      aLo[ks][j] = (short)lb;
    }
  }

  float b1[4], b2[4];
  int i1[4], i2[4];
  #pragma unroll
  for (int r = 0; r < 4; ++r) { b1[r] = INFINITY; b2[r] = INFINITY; i1[r] = 0x7fffffff; i2[r] = 0x7fffffff; }

  // staging map (octet-major dest, conflict-free both sides):
  //   thread t: code n = t&15 of the chunk; octets o0 = t>>4, o1 = 16+(t>>4)
  //   src: embHi[(ch*16+n)*256 + o*8], 16B each (16 rows x 64B segments/wave)
  //   dst slots: s0 = o0*16+n = t, s1 = o1*16+n = 256+t (wave-contiguous 1KB)
  const int nCode = t & 15;
  const int oct0 = t >> 4;
  const unsigned short* srcRowBase = embHi + (size_t)nCode * 256 + oct0 * 8;

  {
    short8 p0 = *(const short8*)(srcRowBase);          // chunk 0, octet o0
    short8 p1 = *(const short8*)(srcRowBase + 128);    // chunk 0, octet o1 (+256B)
    *(short8*)(sB + (size_t)t * 8) = p0;
    *(short8*)(sB + (size_t)(256 + t) * 8) = p1;
  }
  __syncthreads();

  for (int ch = 0; ch < 64; ++ch) {
    const int cur = ch & 1;
    short8 p0, p1;
    if (ch < 63) {   // load chunk ch+1 into regs; latency hidden by compute
      const unsigned short* src = srcRowBase + (size_t)(ch + 1) * 16 * 256;
      p0 = *(const short8*)(src);
      p1 = *(const short8*)(src + 128);
    }
    f32x4 acc = {0.f, 0.f, 0.f, 0.f};
    const unsigned short* bbuf = sB + cur * 4096;
    #pragma unroll
    for (int ks = 0; ks < 8; ++ks) {
      // slot (ks*4+quad)*16 + lane15: wave reads contiguous 1KB, 0 conflicts
      short8 bfrag = *(const short8*)(bbuf + (size_t)(((ks * 4 + quad) * 16) + lane15) * 8);
      acc = __builtin_amdgcn_mfma_f32_16x16x32_bf16(aHi[ks], bfrag, acc, 0, 0, 0);
      acc = __builtin_amdgcn_mfma_f32_16x16x32_bf16(aLo[ks], bfrag, acc, 0, 0, 0);
    }
    const int n = ch * 16 + lane15;
    const float en = sNorm[n];
    #pragma unroll
    for (int r = 0; r < 4; ++r) {
      float s = fmaf(-2.0f, acc[r], en);
      if (s < b1[r])      { b2[r] = b1[r]; i2[r] = i1[r]; b1[r] = s; i1[r] = n; }
      else if (s < b2[r]) { b2[r] = s; i2[r] = n; }
    }
    if (ch < 63) {
      __syncthreads();   // all waves done reading buf[1-cur] (prev chunk)
      unsigned short* nb = sB + (1 - cur) * 4096;
      *(short8*)(nb + (size_t)t * 8) = p0;
      *(short8*)(nb + (size_t)(256 + t) * 8) = p1;
      __syncthreads();   // writes visible before next chunk's reads
    }
  }

  // butterfly top-2 merge across the 16 lanes sharing each pixel
  #pragma unroll
  for (int m = 1; m <= 8; m <<= 1) {
    #pragma unroll
    for (int r = 0; r < 4; ++r) {
      float ob1 = __shfl_xor(b1[r], m), ob2 = __shfl_xor(b2[r], m);
      int oi1 = __shfl_xor(i1[r], m), oi2 = __shfl_xor(i2[r], m);
      bool aF = (b1[r] < ob1) || (b1[r] == ob1 && i1[r] < oi1);
      float w1 = aF ? b1[r] : ob1;  int wi1 = aF ? i1[r] : oi1;
      float lf = aF ? ob1 : b1[r];  int lfi = aF ? oi1 : i1[r];
      float ws = aF ? b2[r] : ob2;  int wsi = aF ? i2[r] : oi2;
      bool sF = (ws < lf) || (ws == lf && wsi < lfi);
      b1[r] = w1; i1[r] = wi1;
      b2[r] = sF ? ws : lf; i2[r] = sF ? wsi : lfi;
    }
  }
  if (lane15 == 0) {
    #pragma unroll
    for (int r = 0; r < 4; ++r) {
      const int pix = pix0 + w * 16 + quad * 4 + r;
      if (b2[r] - b1[r] >= MARGIN_S) {
        selIdx[pix] = i1[r];
        out[OUT_IDX + pix] = (float)i1[r];
      } else {
        int pos = atomicAdd(count, 1);
        worklist[pos] = pix;
      }
    }
  }
}

// ---------------- k_refine v3: LDS mini-GEMM exact re-scan ------------------
// 1024 blocks x 256 threads. Group = RG(8) pixels; wave w covers pixels
// 2w,2w+1 (one per half-wave); lane&31 owns one code of each RTILE(32) tile.
// Codebook tile staged coalesced into LDS (rows padded to 260 floats).
// Dot = validated sequential ascending-c fp32 FMA chain, operands from LDS.
__launch_bounds__(256, 2)
__global__ void k_refine(const float* __restrict__ lat, const float* __restrict__ emb,
                         const float* __restrict__ enormQ,
                         const int* __restrict__ count, const int* __restrict__ worklist,
                         int* __restrict__ selIdx, float* __restrict__ out) {
  __shared__ __align__(16) float sE[RTILE * RSTRIDE];   // 33,280 B
  __shared__ __align__(16) float sX[RG * RSTRIDE];      // 8,320 B
  __shared__ float sSx[RG];
  const int t = threadIdx.x;
  const int cnt = *count;
  if (cnt == 0) return;
  const int ngroups = (cnt + RG - 1) / RG;
  const int w = t >> 6, lane = t & 63;
  const int sub = lane >> 5;           // half-wave: 0 or 1
  const int kLane = lane & 31;         // code slot within tile
  const int pixSlot = w * 2 + sub;     // 0..7

  for (int g = blockIdx.x; g < ngroups; g += gridDim.x) {
    // ---- stage RG pixels' latents (tail pixels clamped, never written) ----
    {
      const int p = t >> 5, c0 = t & 31;    // 32 threads per pixel
      int wi = g * RG + p; if (wi >= cnt) wi = cnt - 1;
      const int pix = worklist[wi];
      const float* latB = lat + (size_t)(pix >> 10) * BSTRIDE + (pix & 1023);
      #pragma unroll
      for (int i = 0; i < 8; ++i) {
        int c = c0 + 32 * i;
        sX[p * RSTRIDE + c] = latB[(size_t)c * 1024];
      }
    }
    __syncthreads();
    // ---- per-pixel numpy-pairwise Sx (threads 0..RG-1) ----
    if (t < RG) {
      const float* a0 = sX + t * RSTRIDE;
      float blk[2];
      #pragma unroll
      for (int h = 0; h < 2; ++h) {
        const float* a = a0 + h * 128;
        float r[8];
        #pragma unroll
        for (int j = 0; j < 8; ++j) r[j] = __fmul_rn(a[j], a[j]);
        for (int i = 8; i < 128; i += 8)
          #pragma unroll
          for (int j = 0; j < 8; ++j) r[j] = __fadd_rn(r[j], __fmul_rn(a[i+j], a[i+j]));
        blk[h] = __fadd_rn(__fadd_rn(__fadd_rn(r[0], r[1]), __fadd_rn(r[2], r[3])),
                           __fadd_rn(__fadd_rn(r[4], r[5]), __fadd_rn(r[6], r[7])));
      }
      sSx[t] = __fadd_rn(blk[0], blk[1]);
    }

    float best = INFINITY; int bi = 0x7fffffff;
    const float* xrow = sX + pixSlot * RSTRIDE;
    for (int tile = 0; tile < 32; ++tile) {
      __syncthreads();   // prev-tile reads done (also orders sSx writes)
      // stage tile: 32 rows x 256 floats (64 float4/row; 8 threads/row x 8)
      {
        const int r = t >> 3, q0 = t & 7;   // 8 threads per row
        const float* src = emb + (size_t)(tile * RTILE + r) * 256;
        #pragma unroll
        for (int i = 0; i < 8; ++i) {
          int q = q0 + 8 * i;
          *(float4*)(sE + r * RSTRIDE + q * 4) = *(const float4*)(src + q * 4);
        }
      }
      __syncthreads();
      // exact ascending-c chain from LDS
      const float* erow = sE + kLane * RSTRIDE;
      float d = 0.f;
      for (int c = 0; c < 256; c += 4) {
        float4 xv = *(const float4*)(xrow + c);
        float4 ev = *(const float4*)(erow + c);
        d = fmaf(xv.x, ev.x, d); d = fmaf(xv.y, ev.y, d);
        d = fmaf(xv.z, ev.z, d); d = fmaf(xv.w, ev.w, d);
      }
      const int k = tile * RTILE + kLane;
      float dq = __fsub_rn(__fadd_rn(sSx[pixSlot], enormQ[k]), __fmul_rn(2.0f, d));
      if (dq < best) { best = dq; bi = k; }   // ascending k per lane
    }
    // lexicographic reduce within each half-wave (pre-update read semantics
    // keep the tree correct; polluted upper lanes are never re-consumed)
    for (int off = 16; off > 0; off >>= 1) {
      float ob = __shfl_down(best, off);
      int oi = __shfl_down(bi, off);
      if (ob < best || (ob == best && oi < bi)) { best = ob; bi = oi; }
    }
    if (kLane == 0) {
      const int wi = g * RG + pixSlot;
      if (wi < cnt) {
        const int pix = worklist[wi];
        selIdx[pix] = bi;
        out[OUT_IDX + pix] = (float)bi;
      }
    }
    __syncthreads();   // sX/sSx stable until all waves finish the group
  }
}

// ---------------- k_gather: gather + straight-through + loss ----------------
__global__ void k_gather(const float* __restrict__ lat, const float* __restrict__ emb,
                         const int* __restrict__ selIdx,
                         float* __restrict__ out, double* __restrict__ lossAcc) {
  __shared__ int sIdx[64];
  const int t = threadIdx.x;
  const int pix0 = blockIdx.x * 64;
  const int b = pix0 >> 10;
  const int hw0 = pix0 & 1023;
  const float* latBase = lat + (size_t)b * BSTRIDE + hw0;

  if (t < 64) sIdx[t] = selIdx[pix0 + t];
  __syncthreads();

  const int cSub = t >> 4;
  const int p4 = (t & 15) * 4;
  const int k0 = sIdx[p4], k1 = sIdx[p4+1], k2 = sIdx[p4+2], k3 = sIdx[p4+3];
  double lsum = 0.0;
  #pragma unroll 4
  for (int i = 0; i < 16; ++i) {
    int c = i * 16 + cSub;
    float4 l = *(const float4*)(latBase + (size_t)c * 1024 + p4);
    float q0 = emb[k0 * DIM + c], q1 = emb[k1 * DIM + c],
          q2 = emb[k2 * DIM + c], q3 = emb[k3 * DIM + c];
    float d0 = q0 - l.x, d1 = q1 - l.y, d2 = q2 - l.z, d3 = q3 - l.w;
    float4 o; o.x = l.x + d0; o.y = l.y + d1; o.z = l.z + d2; o.w = l.w + d3;
    *(float4*)(out + (size_t)b * BSTRIDE + (size_t)c * 1024 + hw0 + p4) = o;
    lsum += (double)d0*d0 + (double)d1*d1 + (double)d2*d2 + (double)d3*d3;
  }
  for (int off = 32; off > 0; off >>= 1) lsum += __shfl_down(lsum, off);
  if ((t & 63) == 0) atomicAdd(lossAcc, lsum);
}

__global__ void k_loss(const double* __restrict__ lossAcc, float* __restrict__ out) {
  double m = *lossAcc * (1.0 / 16777216.0);
  out[OUT_LOSS] = (float)(1.25 * m);
}

extern "C" void kernel_launch(void* const* d_in, const int* in_sizes, int n_in,
                              void* d_out, int out_size, void* d_ws, size_t ws_size,
                              hipStream_t stream) {
  const float* lat = (const float*)d_in[0];
  const float* emb = (const float*)d_in[1];
  float* out = (float*)d_out;
  char* ws = (char*)d_ws;
  double* lossAcc = (double*)(ws + WS_LOSS);
  int* count = (int*)(ws + WS_COUNT);
  float* enormQ = (float*)(ws + WS_ENORM);
  unsigned short* embHi = (unsigned short*)(ws + WS_EMBH);
  int* selIdx = (int*)(ws + WS_SEL);
  int* worklist = (int*)(ws + WS_WL);

  k_init<<<dim3(256), dim3(256), 0, stream>>>(emb, embHi, enormQ, lossAcc, count);
  k_score<<<dim3(1024), dim3(256), 0, stream>>>(lat, embHi, enormQ, selIdx, out, count, worklist);
  k_refine<<<dim3(1024), dim3(256), 0, stream>>>(lat, emb, enormQ, count, worklist, selIdx, out);
  k_gather<<<dim3(1024), dim3(256), 0, stream>>>(lat, emb, selIdx, out, lossAcc);
  k_loss<<<dim3(1), dim3(1), 0, stream>>>(lossAcc, out);
}